// Round 4
// baseline (4070.906 us; speedup 1.0000x reference)
//
#include <hip/hip_runtime.h>
#include <stdint.h>

typedef _Float16 f16;
typedef _Float16 f16x4 __attribute__((ext_vector_type(4)));
typedef _Float16 f16x8 __attribute__((ext_vector_type(8)));
typedef float f32x4 __attribute__((ext_vector_type(4)));

__device__ __forceinline__ float fsgn(float t) {
  return (t > 0.f) ? 1.f : ((t < 0.f) ? -1.f : 0.f);
}

// async global->LDS, 16B per lane; LDS dest = wave-uniform base + lane*16
__device__ __forceinline__ void ldsld16(const void* g, void* l) {
  __builtin_amdgcn_global_load_lds(
      (const __attribute__((address_space(1))) unsigned int*)(unsigned long long)(uintptr_t)g,
      (__attribute__((address_space(3))) unsigned int*)(unsigned int)(uintptr_t)l,
      16, 0, 0);
}

// ---------------- fused prep ----------------
struct PP {
  const float* g[9];
  const float* be[9];
  const float* m[9];
  const float* v[9];
  const float* b[9];
  const float* ma;
  const float* va;
  const float* mb;
  const float* vb;
};

struct PrepAll {
  const float* w[9];
  f16* wpk[9];
  const float* x;
  f16* s1p;
  PP pp;
  float* prm;
};

__device__ void prep_params_body(const PP& a, float* prm) {
  const int c = threadIdx.x;
  if (c >= 192) return;
  const int CINv[9]  = {3, 192, 160, 96, 192, 192, 192, 192, 192};
  const int COUTv[9] = {192, 160, 96, 192, 192, 192, 192, 192, 10};
  auto alpha = [&](int i) { return a.g[i][c] / sqrtf(a.v[i][c] + 1e-4f); };
  auto beta  = [&](int i, float A) { return a.be[i][c] - a.m[i][c] * A; };

  for (int i = 0; i < 9; ++i) {
    float* base = prm + i * 5 * 192;
    base[c] = (c < COUTv[i]) ? a.b[i][c] : 0.f;
    float P1 = 0.f, P2 = 0.f, P3 = 0.f, P4 = 0.f;
    int bn = -1;
    if (i == 0) bn = 1;
    else if (i == 1) bn = 2;
    else if (i == 3) bn = 4;
    else if (i == 4) bn = 5;
    else if (i == 6) bn = 7;
    if (bn >= 0 && c < CINv[bn]) { float A = alpha(bn); P1 = A; P2 = beta(bn, A); }
    if (i == 7) {  // conv8 epilogue: sign(BN9(BN_b(u)))
      float ib = 1.f / sqrtf(a.vb[c] + 1e-4f);
      float A9 = alpha(8);
      P1 = ib * A9;
      P2 = a.be[8][c] - A9 * (a.m[8][c] + a.mb[c] * ib);
    }
    if (i == 0) {  // conv1 epilogue: BN_a (no affine) between relus
      P3 = 1.f / sqrtf(a.va[c] + 1e-4f);
      P4 = a.ma[c] * P3;
    }
    base[192 + c] = P1;
    base[384 + c] = P2;
    base[576 + c] = P3;
    base[768 + c] = P4;
  }
  { float A = (c < 96) ? alpha(3) : 0.f;
    prm[45 * 192 + c] = A; prm[46 * 192 + c] = (c < 96) ? beta(3, A) : 0.f; }
  { float A = alpha(6);
    prm[47 * 192 + c] = A; prm[48 * 192 + c] = beta(6, A); }
  { float A = (c < 3) ? alpha(0) : 0.f;
    prm[49 * 192 + c] = A; prm[50 * 192 + c] = (c < 3) ? beta(0, A) : 0.f; }
}

// pack W into MFMA A-fragment order:
// wpk[cob][kc][b][lane][0..7]=hi, [8..15]=lo ; lane=(kk>>3)*16 + (co&15), j=kk&7
__device__ void prep_w_body(const float* __restrict__ w, f16* __restrict__ wpk, int idx,
                            int Co, int Cin, int KH, int KW, int KP, int mode) {
  const int co = idx / KP;
  const int k = idx - co * KP;
  float val = 0.f;
  if (co < Co) {
    if (mode == 0) {
      if (k < Cin) val = w[(size_t)co * Cin + k];
    } else if (mode == 1) {  // k = (kh*KW+kw)*Cin + c
      int tap = k / Cin, cc = k - tap * Cin;
      int kh = tap / KW, kw = tap - kh * KW;
      val = w[(((size_t)co * Cin + cc) * KH + kh) * KW + kw];
    } else {  // L1: k = kh*16 + kw*3 + c
      int kh = k >> 4, r = k & 15;
      if (kh < 5 && r < 15) {
        int kw = r / 3, cc = r - kw * 3;
        val = w[(((size_t)co * 3 + cc) * 5 + kh) * 5 + kw];
      }
    }
  }
  f16 h = (f16)val;
  float hf = (float)h;
  if (fabsf(hf) < 6.1035e-5f) { h = (f16)0.f; hf = 0.f; }  // no subnormal hi into MFMA
  f16 l = (f16)((val - hf) * 4096.f);                      // lo pre-scaled 2^12

  const int NCH = KP >> 5;
  const int cob = co >> 6, b = (co >> 4) & 3, l15 = co & 15;
  const int kc = k >> 5, kk = k & 31;
  const size_t off = ((((size_t)cob * NCH + kc) * 4 + b) * 64 + ((kk >> 3) * 16 + l15)) * 16 + (kk & 7);
  wpk[off] = h;
  wpk[off + 8] = l;
}

// segment starts: blk0=params; w-layers; then s1
__constant__ int WB[10] = {1, 73, 217, 297, 2097, 2241, 2385, 3681, 3825, 3873};

__global__ void prep_all(PrepAll A) {
  const int b = blockIdx.x;
  if (b == 0) { prep_params_body(A.pp, A.prm); return; }
  if (b < 3873) {
    static const int COv[9]  = {192, 192, 128, 192, 192, 192, 192, 192, 64};  // CoP
    static const int Cov[9]  = {192, 160, 96, 192, 192, 192, 192, 192, 10};   // Co
    static const int CIv[9]  = {3, 192, 160, 96, 192, 192, 192, 192, 192};
    static const int KHv[9]  = {5, 1, 1, 5, 1, 1, 3, 1, 1};
    static const int KPv[9]  = {96, 192, 160, 2400, 192, 192, 1728, 192, 192};
    static const int MDv[9]  = {2, 0, 0, 1, 0, 0, 1, 0, 0};
    int i = 0;
    while (b >= WB[i + 1]) ++i;
    const int idx = (b - WB[i]) * 256 + threadIdx.x;
    if (idx < COv[i] * KPv[i])
      prep_w_body(A.w[i], A.wpk[i], idx, Cov[i], CIv[i], KHv[i], KHv[i], KPv[i], MDv[i]);
    return;
  }
  // s1: sign(BN1(x)) into padded NHWC [256][36][36][3]
  const int idx = (b - 3873) * 256 + threadIdx.x;
  if (idx >= 256 * 36 * 36 * 3) return;
  int c = idx % 3;
  int t = idx / 3;
  int wp = t % 36; t /= 36;
  int hp = t % 36;
  int n = t / 36;
  int h = hp - 2, w = wp - 2;
  f16 s = (f16)0.f;
  if (h >= 0 && h < 32 && w >= 0 && w < 32) {
    float al = A.pp.g[0][c] / sqrtf(A.pp.v[0][c] + 1e-4f);
    float be = A.pp.be[0][c] - A.pp.m[0][c] * al;
    float xv = A.x[((size_t)(n * 3 + c) * 32 + h) * 32 + w];
    s = (f16)fsgn(xv * al + be);
  }
  A.s1p[idx] = s;
}

// ---------------- pool (+BN+sign) into padded NHWC ----------------
template <int HIN, int CH, int HOUT, int HPAD, int POFF, bool AVG>
__global__ void poolk(const float* __restrict__ in, f16* __restrict__ out,
                      const float* __restrict__ pa, const float* __restrict__ pb) {
  constexpr int C4 = CH / 4;
  const int idx = blockIdx.x * 256 + threadIdx.x;
  if (idx >= 256 * HPAD * HPAD * C4) return;
  int c4 = idx % C4;
  int t = idx / C4;
  int wp = t % HPAD; t /= HPAD;
  int hp = t % HPAD;
  int n = t / HPAD;
  int h = hp - POFF, w = wp - POFF;
  f16x4 res;
  res[0] = res[1] = res[2] = res[3] = (f16)0.f;
  if (h >= 0 && h < HOUT && w >= 0 && w < HOUT) {
    float acc[4];
#pragma unroll
    for (int i = 0; i < 4; ++i) acc[i] = AVG ? 0.f : -1e30f;
#pragma unroll
    for (int i = 0; i < 3; ++i) {
      int yh = 2 * h - 1 + i;
      if (yh < 0 || yh >= HIN) continue;
#pragma unroll
      for (int j = 0; j < 3; ++j) {
        int yw = 2 * w - 1 + j;
        if (yw < 0 || yw >= HIN) continue;
        f32x4 vv = *(const f32x4*)(in + ((size_t)(n * HIN + yh) * HIN + yw) * CH + c4 * 4);
#pragma unroll
        for (int k = 0; k < 4; ++k) acc[k] = AVG ? (acc[k] + vv[k]) : fmaxf(acc[k], vv[k]);
      }
    }
    f32x4 A = *(const f32x4*)(pa + c4 * 4);
    f32x4 B = *(const f32x4*)(pb + c4 * 4);
#pragma unroll
    for (int k = 0; k < 4; ++k) {
      float xv = AVG ? (acc[k] / 9.f) : acc[k];
      res[k] = (f16)fsgn(xv * A[k] + B[k]);
    }
  }
  *(f16x4*)(out + (size_t)idx * 4) = res;
}

// ---------------- implicit-GEMM MFMA conv ----------------
// D[co][m] = W[co][k] * P[k][m]; block = 256 m x 64 co, 4 waves (wave: 64m x 64co, 4x4 frags)
// W in registers (fragment-packed global), P 4-deep LDS pipeline with counted vmcnt.
// MODE: 0=1x1, 1=taps-outer (padded input), 2=L1 packed (kh*16+kw*3+c)
// EPI:  0=bias,relu,affine,sign(f16)  1=+BN_a relu between  2=bias,relu->f32  3=bias,relu,mean->out
template <int MODE, int EPI, int LOG_HW, int LOG_W, int CIN, int COP, int COUT,
          int KH, int KW, int HP, int WP, int NCH, int CCH>
__global__ __launch_bounds__(256, 2) void convk(
    const f16* __restrict__ sin, const f16* __restrict__ wpk,
    const float* __restrict__ prm, void* __restrict__ outp) {
  static_assert(NCH >= 3, "pipeline needs >=3 chunks");
  constexpr int NCOB = COP / 64;
  constexpr int HWm = (1 << LOG_HW) - 1;
  constexpr int Wm = (1 << LOG_W) - 1;

  const int tid = threadIdx.x;
  const int wid = tid >> 6;
  const int lane = tid & 63;
  const int bid = blockIdx.x;
  const int mb = bid / NCOB;
  const int cob = bid - mb * NCOB;

  __shared__ __align__(16) char smem[65536];  // 4 x 16K Ps buffers

  const int pr = lane >> 2;   // row within 16-row staging group
  const int pg = lane & 3;    // physical granule

  // per-lane staging base addresses (granule XOR-swizzle folded into global source)
  const f16* psrc[4];
#pragma unroll
  for (int q = 0; q < 4; ++q) {
    const int j = wid * 4 + q;
    const int r = j * 16 + pr;              // Ps row (m within tile)
    const int g = pg ^ ((r >> 1) & 3);      // logical granule stored at phys pg
    const int m = mb * 256 + r;
    if constexpr (MODE == 0) {
      psrc[q] = sin + (size_t)m * CIN + g * 8;
    } else if constexpr (MODE == 1) {
      const int n = m >> LOG_HW;
      const int hw = m & HWm;
      const int h = hw >> LOG_W;
      const int w = hw & Wm;
      psrc[q] = sin + ((size_t)(n * HP + h) * WP + w) * CIN + g * 8;
    } else {
      const int n = m >> 10;
      const int hw = m & 1023;
      const int h = hw >> 5;
      const int w = hw & 31;
      const int khg = g >> 1;                     // kh = 2*kc + (g>>1)
      const int sel = g & 1;                      // k%16 = 0 or 8
      psrc[q] = sin + ((size_t)(n * 36 + h + khg) * 36 + (w + (sel ? 2 : 0))) * 3 + (sel ? 2 : 0);
    }
  }

  auto stage = [&](int kc, int cur) {
    char* lb = smem + cur * 16384;
    int coff;
    if constexpr (MODE == 0) coff = kc * 32;
    else if constexpr (MODE == 2) coff = kc * 216;  // 2 kh-rows per chunk
    else {
      const int tap = kc / CCH;
      const int cc = kc - tap * CCH;
      const int kh = tap / KW;
      const int kw = tap - kh * KW;
      coff = (kh * WP + kw) * CIN + cc * 32;
    }
#pragma unroll
    for (int q = 0; q < 4; ++q) ldsld16(psrc[q] + coff, lb + (wid * 4 + q) * 1024);
  };

  // W fragments: per chunk 4 co-subtiles x (hi,lo), 16B each, packed per-lane
  auto loadW = [&](int kc, f16x8 (&W)[8]) {
    const f16* bp = wpk + ((size_t)(cob * NCH + kc) * 4096) + lane * 16;
#pragma unroll
    for (int b = 0; b < 4; ++b) {
      W[b * 2 + 0] = *(const f16x8*)(bp + b * 1024);
      W[b * 2 + 1] = *(const f16x8*)(bp + b * 1024 + 8);
    }
  };

  const int ln15 = lane & 15;
  const int xg = (lane >> 4) ^ ((ln15 >> 1) & 3);  // swizzled read granule
  const int rdB = wid * 4096 + ln15 * 64 + xg * 16;

  f32x4 aH[4][4], aL[4][4];
#pragma unroll
  for (int a = 0; a < 4; ++a)
#pragma unroll
    for (int b = 0; b < 4; ++b) {
      aH[a][b] = (f32x4){0.f, 0.f, 0.f, 0.f};
      aL[a][b] = (f32x4){0.f, 0.f, 0.f, 0.f};
    }

  f16x8 wEv[8], wOd[8];  // W(s) in wEv for even s, wOd for odd s

  auto compute = [&](int s3, const f16x8 (&WC)[8]) {
    const char* cb = smem + s3 * 16384;
    f16x8 Bf[4];
#pragma unroll
    for (int a = 0; a < 4; ++a) Bf[a] = *(const f16x8*)(cb + rdB + a * 1024);
#pragma unroll
    for (int b = 0; b < 4; ++b) {
#pragma unroll
      for (int a = 0; a < 4; ++a) {
        aH[a][b] = __builtin_amdgcn_mfma_f32_16x16x32_f16(WC[b * 2 + 0], Bf[a], aH[a][b], 0, 0, 0);
        aL[a][b] = __builtin_amdgcn_mfma_f32_16x16x32_f16(WC[b * 2 + 1], Bf[a], aL[a][b], 0, 0, 0);
      }
    }
  };

  // prologue: fill 3 Ps buffers, W(0)
  stage(0, 0);
  stage(1, 1);
  stage(2, 2);
  loadW(0, wEv);
  __syncthreads();  // drains vmcnt(0)

  int s = 0;
  // FULL iterations: s = 0 .. NCH-4
  for (; s < NCH - 3; ++s) {
    stage(s + 3, (s + 3) & 3);
    if (s & 1) { loadW(s + 1, wEv); compute(s & 3, wOd); }
    else       { loadW(s + 1, wOd); compute(s & 3, wEv); }
    // current iter's 12 vmem ops (4 stage + 8 W) may stay in flight; all older retired
    asm volatile("s_waitcnt vmcnt(12)" ::: "memory");
    __builtin_amdgcn_s_barrier();
  }
  // tail: two iterations with W-load but no stage
#pragma unroll
  for (int r = 0; r < 2; ++r) {
    if (s & 1) { loadW(s + 1, wEv); compute(s & 3, wOd); }
    else       { loadW(s + 1, wOd); compute(s & 3, wEv); }
    asm volatile("s_waitcnt vmcnt(8)" ::: "memory");
    __builtin_amdgcn_s_barrier();
    ++s;
  }
  // last iteration: compute only
  if (s & 1) compute(s & 3, wOd);
  else       compute(s & 3, wEv);

  constexpr float LSC = 1.f / 4096.f;
  const int hi4 = (lane >> 4) * 4;

  if constexpr (EPI == 3) {  // conv9: bias, relu, mean over 64 pixels -> d_out
    float red[4] = {0.f, 0.f, 0.f, 0.f};
    const f32x4 bi = *(const f32x4*)(prm + hi4);
#pragma unroll
    for (int a = 0; a < 4; ++a)
#pragma unroll
      for (int i = 0; i < 4; ++i)
        red[i] += fmaxf(aH[a][0][i] + aL[a][0][i] * LSC + bi[i], 0.f);
#pragma unroll
    for (int i = 0; i < 4; ++i) {
      red[i] += __shfl_xor(red[i], 1);
      red[i] += __shfl_xor(red[i], 2);
      red[i] += __shfl_xor(red[i], 4);
      red[i] += __shfl_xor(red[i], 8);
    }
    if (ln15 == 0) {
      const int n = mb * 4 + wid;  // wave owns one image (64 pixels)
      float* o = (float*)outp;
#pragma unroll
      for (int i = 0; i < 4; ++i) {
        const int co = hi4 + i;
        if (co < 10) o[n * 10 + co] = red[i] * (1.f / 64.f);
      }
    }
  } else {
#pragma unroll
    for (int a = 0; a < 4; ++a) {
      const int m = mb * 256 + wid * 64 + a * 16 + ln15;
#pragma unroll
      for (int b = 0; b < 4; ++b) {
        const int co = cob * 64 + b * 16 + hi4;
        if (co < COUT) {
          const f32x4 bi = *(const f32x4*)(prm + co);
          f32x4 v;
#pragma unroll
          for (int i = 0; i < 4; ++i)
            v[i] = fmaxf(aH[a][b][i] + aL[a][b][i] * LSC + bi[i], 0.f);
          if constexpr (EPI == 1) {  // BN_a (no affine) + relu
            const f32x4 ia = *(const f32x4*)(prm + 576 + co);
            const f32x4 mi = *(const f32x4*)(prm + 768 + co);
#pragma unroll
            for (int i = 0; i < 4; ++i) v[i] = fmaxf(v[i] * ia[i] - mi[i], 0.f);
          }
          if constexpr (EPI == 2) {
            *(f32x4*)((float*)outp + (size_t)m * COUT + co) = v;
          } else {
            const f32x4 al = *(const f32x4*)(prm + 192 + co);
            const f32x4 be = *(const f32x4*)(prm + 384 + co);
            f16x4 sgn;
#pragma unroll
            for (int i = 0; i < 4; ++i) sgn[i] = (f16)fsgn(v[i] * al[i] + be[i]);
            *(f16x4*)((f16*)outp + (size_t)m * COUT + co) = sgn;
          }
        }
      }
    }
  }
}

// ---------------- host ----------------
extern "C" void kernel_launch(void* const* d_in, const int* in_sizes, int n_in,
                              void* d_out, int out_size, void* d_ws, size_t ws_size,
                              hipStream_t stream) {
  (void)in_sizes; (void)n_in; (void)out_size; (void)ws_size;
  auto IN = [&](int i) { return (const float*)d_in[i]; };
  char* ws = (char*)d_ws;

  // ws layout
  const size_t OFF_W = 65536;  // PRM: 51*192*4 = 39168 bytes at 0
  // packed W bytes per layer: CoP*KP*4
  static const size_t WSZ[9] = {73728, 147456, 81920, 1843200, 147456, 147456, 1327104, 147456, 49152};
  f16* WPK[9];
  {
    size_t o = OFF_W;
    for (int i = 0; i < 9; ++i) { WPK[i] = (f16*)(ws + o); o += WSZ[i]; }
  }
  const size_t OFF_ACT = OFF_W + 3964928;
  const size_t SLOT_A = OFF_ACT;
  const size_t SLOT_B = SLOT_A + 83890176;

  f16*   S1P = (f16*)(ws + SLOT_A);
  f16*   S2  = (f16*)(ws + SLOT_B);
  f16*   S3  = (f16*)(ws + SLOT_A);
  float* Y3  = (float*)(ws + SLOT_B);
  f16*   S4P = (f16*)(ws + SLOT_A);
  f16*   S5  = (f16*)(ws + SLOT_B);
  f16*   S6  = (f16*)(ws + SLOT_A);
  float* Y6  = (float*)(ws + SLOT_B);
  f16*   S7P = (f16*)(ws + SLOT_A);
  f16*   S8  = (f16*)(ws + SLOT_B);
  f16*   S9  = (f16*)(ws + SLOT_A);

  float* PRM = (float*)ws;

  PrepAll PA;
  for (int i = 0; i < 9; ++i) {
    PA.pp.g[i]  = IN(1 + i * 6 + 0);
    PA.pp.be[i] = IN(1 + i * 6 + 1);
    PA.pp.m[i]  = IN(1 + i * 6 + 2);
    PA.pp.v[i]  = IN(1 + i * 6 + 3);
    PA.pp.b[i]  = IN(1 + i * 6 + 5);
    PA.w[i] = IN(1 + i * 6 + 4);
    PA.wpk[i] = WPK[i];
  }
  PA.pp.ma = IN(55); PA.pp.va = IN(56); PA.pp.mb = IN(57); PA.pp.vb = IN(58);
  PA.x = IN(0);
  PA.s1p = S1P;
  PA.prm = PRM;

  prep_all<<<7761, 256, 0, stream>>>(PA);

  // convs: <MODE,EPI,LOG_HW,LOG_W,CIN,COP,COUT,KH,KW,HP,WP,NCH,CCH>
  convk<2, 1, 10, 5, 3, 192, 192, 5, 5, 36, 36, 3, 1><<<1024 * 3, 256, 0, stream>>>(
      S1P, WPK[0], PRM + 0 * 960, S2);
  convk<0, 0, 10, 5, 192, 192, 160, 1, 1, 0, 0, 6, 1><<<1024 * 3, 256, 0, stream>>>(
      S2, WPK[1], PRM + 1 * 960, S3);
  convk<0, 2, 10, 5, 160, 128, 96, 1, 1, 0, 0, 5, 1><<<1024 * 2, 256, 0, stream>>>(
      S3, WPK[2], PRM + 2 * 960, Y3);
  poolk<32, 96, 16, 20, 2, false><<<9600, 256, 0, stream>>>(Y3, S4P, PRM + 45 * 192, PRM + 46 * 192);
  convk<1, 0, 8, 4, 96, 192, 192, 5, 5, 20, 20, 75, 3><<<256 * 3, 256, 0, stream>>>(
      S4P, WPK[3], PRM + 3 * 960, S5);
  convk<0, 0, 8, 4, 192, 192, 192, 1, 1, 0, 0, 6, 1><<<256 * 3, 256, 0, stream>>>(
      S5, WPK[4], PRM + 4 * 960, S6);
  convk<0, 2, 8, 4, 192, 192, 192, 1, 1, 0, 0, 6, 1><<<256 * 3, 256, 0, stream>>>(
      S6, WPK[5], PRM + 5 * 960, Y6);
  poolk<16, 192, 8, 10, 1, true><<<4800, 256, 0, stream>>>(Y6, S7P, PRM + 47 * 192, PRM + 48 * 192);
  convk<1, 0, 6, 3, 192, 192, 192, 3, 3, 10, 10, 54, 6><<<64 * 3, 256, 0, stream>>>(
      S7P, WPK[6], PRM + 6 * 960, S8);
  convk<0, 0, 6, 3, 192, 192, 192, 1, 1, 0, 0, 6, 1><<<64 * 3, 256, 0, stream>>>(
      S8, WPK[7], PRM + 7 * 960, S9);
  convk<0, 3, 6, 3, 192, 64, 10, 1, 1, 0, 0, 6, 1><<<64, 256, 0, stream>>>(
      S9, WPK[8], PRM + 8 * 960, d_out);
}

// Round 5
// 630.476 us; speedup vs baseline: 6.4569x; 6.4569x over previous
//
#include <hip/hip_runtime.h>
#include <stdint.h>

typedef _Float16 f16;
typedef _Float16 f16x4 __attribute__((ext_vector_type(4)));
typedef _Float16 f16x8 __attribute__((ext_vector_type(8)));
typedef float f32x4 __attribute__((ext_vector_type(4)));

__device__ __forceinline__ float fsgn(float t) {
  return (t > 0.f) ? 1.f : ((t < 0.f) ? -1.f : 0.f);
}

// async global->LDS, 16B per lane; LDS dest = wave-uniform base + lane*16
__device__ __forceinline__ void ldsld16(const void* g, void* l) {
  __builtin_amdgcn_global_load_lds(
      (const __attribute__((address_space(1))) unsigned int*)(unsigned long long)(uintptr_t)g,
      (__attribute__((address_space(3))) unsigned int*)(unsigned int)(uintptr_t)l,
      16, 0, 0);
}

// ---------------- fused prep ----------------
struct PP {
  const float* g[9];
  const float* be[9];
  const float* m[9];
  const float* v[9];
  const float* b[9];
  const float* ma;
  const float* va;
  const float* mb;
  const float* vb;
};

struct PrepAll {
  const float* w[9];
  f16* wh[9];
  f16* wl[9];
  const float* x;
  f16* s1p;
  PP pp;
  float* prm;
};

__device__ void prep_params_body(const PP& a, float* prm) {
  const int c = threadIdx.x;
  if (c >= 192) return;
  const int CINv[9]  = {3, 192, 160, 96, 192, 192, 192, 192, 192};
  const int COUTv[9] = {192, 160, 96, 192, 192, 192, 192, 192, 10};
  auto alpha = [&](int i) { return a.g[i][c] / sqrtf(a.v[i][c] + 1e-4f); };
  auto beta  = [&](int i, float A) { return a.be[i][c] - a.m[i][c] * A; };

  for (int i = 0; i < 9; ++i) {
    float* base = prm + i * 5 * 192;
    base[c] = (c < COUTv[i]) ? a.b[i][c] : 0.f;
    float P1 = 0.f, P2 = 0.f, P3 = 0.f, P4 = 0.f;
    int bn = -1;
    if (i == 0) bn = 1;
    else if (i == 1) bn = 2;
    else if (i == 3) bn = 4;
    else if (i == 4) bn = 5;
    else if (i == 6) bn = 7;
    if (bn >= 0 && c < CINv[bn]) { float A = alpha(bn); P1 = A; P2 = beta(bn, A); }
    if (i == 7) {  // conv8 epilogue: sign(BN9(BN_b(u)))
      float ib = 1.f / sqrtf(a.vb[c] + 1e-4f);
      float A9 = alpha(8);
      P1 = ib * A9;
      P2 = a.be[8][c] - A9 * (a.m[8][c] + a.mb[c] * ib);
    }
    if (i == 0) {  // conv1 epilogue: BN_a (no affine) between relus
      P3 = 1.f / sqrtf(a.va[c] + 1e-4f);
      P4 = a.ma[c] * P3;
    }
    base[192 + c] = P1;
    base[384 + c] = P2;
    base[576 + c] = P3;
    base[768 + c] = P4;
  }
  { float A = (c < 96) ? alpha(3) : 0.f;
    prm[45 * 192 + c] = A; prm[46 * 192 + c] = (c < 96) ? beta(3, A) : 0.f; }
  { float A = alpha(6);
    prm[47 * 192 + c] = A; prm[48 * 192 + c] = beta(6, A); }
  { float A = (c < 3) ? alpha(0) : 0.f;
    prm[49 * 192 + c] = A; prm[50 * 192 + c] = (c < 3) ? beta(0, A) : 0.f; }
}

__device__ void prep_w_body(const float* __restrict__ w, f16* __restrict__ wh,
                            f16* __restrict__ wl, int idx,
                            int Co, int Cin, int KH, int KW, int KP, int mode) {
  const int co = idx / KP;
  const int k = idx - co * KP;
  float val = 0.f;
  if (co < Co) {
    if (mode == 0) {
      if (k < Cin) val = w[(size_t)co * Cin + k];
    } else if (mode == 1) {  // k = (kh*KW+kw)*Cin + c
      int tap = k / Cin, cc = k - tap * Cin;
      int kh = tap / KW, kw = tap - kh * KW;
      val = w[(((size_t)co * Cin + cc) * KH + kh) * KW + kw];
    } else {  // L1: k = kh*16 + kw*3 + c
      int kh = k >> 4, r = k & 15;
      if (kh < 5 && r < 15) {
        int kw = r / 3, cc = r - kw * 3;
        val = w[(((size_t)co * 3 + cc) * 5 + kh) * 5 + kw];
      }
    }
  }
  f16 h = (f16)val;
  float hf = (float)h;
  if (fabsf(hf) < 6.1035e-5f) { h = (f16)0.f; hf = 0.f; }  // no subnormal hi into MFMA
  f16 l = (f16)((val - hf) * 4096.f);                      // lo pre-scaled 2^12
  wh[idx] = h;
  wl[idx] = l;
}

// segment starts: blk0=params; w-layers; then s1
__constant__ int WB[10] = {1, 73, 217, 297, 2097, 2241, 2385, 3681, 3825, 3873};

__global__ void prep_all(PrepAll A) {
  const int b = blockIdx.x;
  if (b == 0) { prep_params_body(A.pp, A.prm); return; }
  if (b < 3873) {
    static const int COv[9]  = {192, 192, 128, 192, 192, 192, 192, 192, 64};  // CoP
    static const int Cov[9]  = {192, 160, 96, 192, 192, 192, 192, 192, 10};   // Co
    static const int CIv[9]  = {3, 192, 160, 96, 192, 192, 192, 192, 192};
    static const int KHv[9]  = {5, 1, 1, 5, 1, 1, 3, 1, 1};
    static const int KPv[9]  = {96, 192, 160, 2400, 192, 192, 1728, 192, 192};
    static const int MDv[9]  = {2, 0, 0, 1, 0, 0, 1, 0, 0};
    int i = 0;
    while (b >= WB[i + 1]) ++i;
    const int idx = (b - WB[i]) * 256 + threadIdx.x;
    if (idx < COv[i] * KPv[i])
      prep_w_body(A.w[i], A.wh[i], A.wl[i], idx, Cov[i], CIv[i], KHv[i], KHv[i], KPv[i], MDv[i]);
    return;
  }
  // s1: sign(BN1(x)) into padded NHWC [256][36][36][3]
  const int idx = (b - 3873) * 256 + threadIdx.x;
  if (idx >= 256 * 36 * 36 * 3) return;
  int c = idx % 3;
  int t = idx / 3;
  int wp = t % 36; t /= 36;
  int hp = t % 36;
  int n = t / 36;
  int h = hp - 2, w = wp - 2;
  f16 s = (f16)0.f;
  if (h >= 0 && h < 32 && w >= 0 && w < 32) {
    float al = A.pp.g[0][c] / sqrtf(A.pp.v[0][c] + 1e-4f);
    float be = A.pp.be[0][c] - A.pp.m[0][c] * al;
    float xv = A.x[((size_t)(n * 3 + c) * 32 + h) * 32 + w];
    s = (f16)fsgn(xv * al + be);
  }
  A.s1p[idx] = s;
}

// ---------------- pool (+BN+sign) into padded NHWC ----------------
template <int HIN, int CH, int HOUT, int HPAD, int POFF, bool AVG>
__global__ void poolk(const float* __restrict__ in, f16* __restrict__ out,
                      const float* __restrict__ pa, const float* __restrict__ pb) {
  constexpr int C4 = CH / 4;
  const int idx = blockIdx.x * 256 + threadIdx.x;
  if (idx >= 256 * HPAD * HPAD * C4) return;
  int c4 = idx % C4;
  int t = idx / C4;
  int wp = t % HPAD; t /= HPAD;
  int hp = t % HPAD;
  int n = t / HPAD;
  int h = hp - POFF, w = wp - POFF;
  f16x4 res;
  res[0] = res[1] = res[2] = res[3] = (f16)0.f;
  if (h >= 0 && h < HOUT && w >= 0 && w < HOUT) {
    float acc[4];
#pragma unroll
    for (int i = 0; i < 4; ++i) acc[i] = AVG ? 0.f : -1e30f;
#pragma unroll
    for (int i = 0; i < 3; ++i) {
      int yh = 2 * h - 1 + i;
      if (yh < 0 || yh >= HIN) continue;
#pragma unroll
      for (int j = 0; j < 3; ++j) {
        int yw = 2 * w - 1 + j;
        if (yw < 0 || yw >= HIN) continue;
        f32x4 vv = *(const f32x4*)(in + ((size_t)(n * HIN + yh) * HIN + yw) * CH + c4 * 4);
#pragma unroll
        for (int k = 0; k < 4; ++k) acc[k] = AVG ? (acc[k] + vv[k]) : fmaxf(acc[k], vv[k]);
      }
    }
    f32x4 A = *(const f32x4*)(pa + c4 * 4);
    f32x4 B = *(const f32x4*)(pb + c4 * 4);
#pragma unroll
    for (int k = 0; k < 4; ++k) {
      float xv = AVG ? (acc[k] / 9.f) : acc[k];
      res[k] = (f16)fsgn(xv * A[k] + B[k]);
    }
  }
  *(f16x4*)(out + (size_t)idx * 4) = res;
}

// ---------------- implicit-GEMM MFMA conv ----------------
// D[co][m] = W[co][k] * P[k][m]; block = 256 m x 64 co, 4 waves (wave: 64m x 64co, 4x4 frags)
// 3-buffer LDS pipeline (Ps+Wh+Wl per buffer), counted vmcnt(6), one raw barrier/iter.
// MODE: 0=1x1, 1=taps-outer (padded input), 2=L1 packed (kh*16+kw*3+c)
// EPI:  0=bias,relu,affine,sign(f16)  1=+BN_a relu between  2=bias,relu->f32  3=bias,relu,mean->out
template <int MODE, int EPI, int LOG_HW, int LOG_W, int CIN, int COP, int COUT,
          int KH, int KW, int HP, int WP, int NCH, int CCH>
__global__ __launch_bounds__(256, 2) void convk(
    const f16* __restrict__ sin, const f16* __restrict__ wh, const f16* __restrict__ wl,
    const float* __restrict__ prm, void* __restrict__ outp) {
  static_assert(NCH >= 3, "pipeline needs >=3 chunks");
  constexpr int NCOB = COP / 64;
  constexpr int HWm = (1 << LOG_HW) - 1;
  constexpr int Wm = (1 << LOG_W) - 1;

  const int tid = threadIdx.x;
  const int wid = tid >> 6;
  const int lane = tid & 63;
  const int bid = blockIdx.x;
  const int mb = bid / NCOB;
  const int cob = bid - mb * NCOB;

  __shared__ __align__(16) char smem[73728];  // 3 x (Ps 16K + Wh 4K + Wl 4K)

  const int pr = lane >> 2;   // row within 16-row staging group
  const int pg = lane & 3;    // physical granule

  // per-lane staging base addresses (granule XOR-swizzle folded into global source)
  const f16* psrc[4];
#pragma unroll
  for (int q = 0; q < 4; ++q) {
    const int j = wid * 4 + q;
    const int r = j * 16 + pr;              // Ps row (m within tile)
    const int g = pg ^ ((r >> 1) & 3);      // logical granule stored at phys pg
    const int m = mb * 256 + r;
    if constexpr (MODE == 0) {
      psrc[q] = sin + (size_t)m * CIN + g * 8;
    } else if constexpr (MODE == 1) {
      const int n = m >> LOG_HW;
      const int hw = m & HWm;
      const int h = hw >> LOG_W;
      const int w = hw & Wm;
      psrc[q] = sin + ((size_t)(n * HP + h) * WP + w) * CIN + g * 8;
    } else {
      const int n = m >> 10;
      const int hw = m & 1023;
      const int h = hw >> 5;
      const int w = hw & 31;
      const int khg = g >> 1;                     // kh = 2*kc + (g>>1)
      const int sel = g & 1;                      // k%16 = 0 or 8
      psrc[q] = sin + ((size_t)(n * 36 + h + khg) * 36 + (w + (sel ? 2 : 0))) * 3 + (sel ? 2 : 0);
    }
  }
  const int wr = wid * 16 + pr;             // Ws row (co within 64-tile)
  const int wgg = pg ^ ((wr >> 1) & 3);
  const f16* wsrc_h = wh + (size_t)(cob * 64 + wr) * (NCH * 32) + wgg * 8;
  const f16* wsrc_l = wl + (size_t)(cob * 64 + wr) * (NCH * 32) + wgg * 8;

  auto stage = [&](int kc, int cur) {
    char* lb = smem + cur * 24576;
    int coff;
    if constexpr (MODE == 0) coff = kc * 32;
    else if constexpr (MODE == 2) coff = kc * 216;  // 2 kh-rows per chunk
    else {
      const int tap = kc / CCH;
      const int cc = kc - tap * CCH;
      const int kh = tap / KW;
      const int kw = tap - kh * KW;
      coff = (kh * WP + kw) * CIN + cc * 32;
    }
#pragma unroll
    for (int q = 0; q < 4; ++q) ldsld16(psrc[q] + coff, lb + (wid * 4 + q) * 1024);
    ldsld16(wsrc_h + kc * 32, lb + 16384 + wid * 1024);
    ldsld16(wsrc_l + kc * 32, lb + 20480 + wid * 1024);
  };

  const int ln15 = lane & 15;
  const int xg = (lane >> 4) ^ ((ln15 >> 1) & 3);  // swizzled read granule
  const int rdB = wid * 4096 + ln15 * 64 + xg * 16;
  const int rdA = 16384 + ln15 * 64 + xg * 16;

  f32x4 aH[4][4], aL[4][4];
#pragma unroll
  for (int a = 0; a < 4; ++a)
#pragma unroll
    for (int b = 0; b < 4; ++b) {
      aH[a][b] = (f32x4){0.f, 0.f, 0.f, 0.f};
      aL[a][b] = (f32x4){0.f, 0.f, 0.f, 0.f};
    }

  auto compute = [&](int cur) {
    const char* cb = smem + cur * 24576;
    f16x8 Bf[4];
#pragma unroll
    for (int a = 0; a < 4; ++a) Bf[a] = *(const f16x8*)(cb + a * 1024 + rdB);
#pragma unroll
    for (int b = 0; b < 4; ++b) {
      const f16x8 Ah = *(const f16x8*)(cb + rdA + b * 1024);
      const f16x8 Al = *(const f16x8*)(cb + rdA + 4096 + b * 1024);
#pragma unroll
      for (int a = 0; a < 4; ++a) {
        aH[a][b] = __builtin_amdgcn_mfma_f32_16x16x32_f16(Ah, Bf[a], aH[a][b], 0, 0, 0);
        aL[a][b] = __builtin_amdgcn_mfma_f32_16x16x32_f16(Al, Bf[a], aL[a][b], 0, 0, 0);
      }
    }
  };

  // prologue: fill buffers 0,1 (12 vmem ops/lane in flight)
  stage(0, 0);
  stage(1, 1);

  // steady state at iter s: queue = [stage(s) (6), stage(s+1) (6)]
  //   vmcnt(6) -> stage(s) complete; barrier; compute(s); issue stage(s+2)
  //   stage(s+2) overwrites buffer (s-1)%3, consumed before this barrier. 1 barrier/iter.
  for (int s = 0; s < NCH; ++s) {
    if (s == NCH - 1) asm volatile("s_waitcnt vmcnt(0)" ::: "memory");
    else              asm volatile("s_waitcnt vmcnt(6)" ::: "memory");
    __builtin_amdgcn_s_barrier();
    const int cur = s % 3;
    compute(cur);
    if (s + 2 < NCH) stage(s + 2, (s + 2) % 3);
  }

  constexpr float LSC = 1.f / 4096.f;
  const int hi4 = (lane >> 4) * 4;

  if constexpr (EPI == 3) {  // conv9: bias, relu, mean over 64 pixels -> d_out
    float red[4] = {0.f, 0.f, 0.f, 0.f};
    const f32x4 bi = *(const f32x4*)(prm + hi4);
#pragma unroll
    for (int a = 0; a < 4; ++a)
#pragma unroll
      for (int i = 0; i < 4; ++i)
        red[i] += fmaxf(aH[a][0][i] + aL[a][0][i] * LSC + bi[i], 0.f);
#pragma unroll
    for (int i = 0; i < 4; ++i) {
      red[i] += __shfl_xor(red[i], 1);
      red[i] += __shfl_xor(red[i], 2);
      red[i] += __shfl_xor(red[i], 4);
      red[i] += __shfl_xor(red[i], 8);
    }
    if (ln15 == 0) {
      const int n = mb * 4 + wid;  // wave owns one image (64 pixels)
      float* o = (float*)outp;
#pragma unroll
      for (int i = 0; i < 4; ++i) {
        const int co = hi4 + i;
        if (co < 10) o[n * 10 + co] = red[i] * (1.f / 64.f);
      }
    }
  } else {
#pragma unroll
    for (int a = 0; a < 4; ++a) {
      const int m = mb * 256 + wid * 64 + a * 16 + ln15;
#pragma unroll
      for (int b = 0; b < 4; ++b) {
        const int co = cob * 64 + b * 16 + hi4;
        if (co < COUT) {
          const f32x4 bi = *(const f32x4*)(prm + co);
          f32x4 v;
#pragma unroll
          for (int i = 0; i < 4; ++i)
            v[i] = fmaxf(aH[a][b][i] + aL[a][b][i] * LSC + bi[i], 0.f);
          if constexpr (EPI == 1) {  // BN_a (no affine) + relu
            const f32x4 ia = *(const f32x4*)(prm + 576 + co);
            const f32x4 mi = *(const f32x4*)(prm + 768 + co);
#pragma unroll
            for (int i = 0; i < 4; ++i) v[i] = fmaxf(v[i] * ia[i] - mi[i], 0.f);
          }
          if constexpr (EPI == 2) {
            *(f32x4*)((float*)outp + (size_t)m * COUT + co) = v;
          } else {
            const f32x4 al = *(const f32x4*)(prm + 192 + co);
            const f32x4 be = *(const f32x4*)(prm + 384 + co);
            f16x4 sgn;
#pragma unroll
            for (int i = 0; i < 4; ++i) sgn[i] = (f16)fsgn(v[i] * al[i] + be[i]);
            *(f16x4*)((f16*)outp + (size_t)m * COUT + co) = sgn;
          }
        }
      }
    }
  }
}

// ---------------- host ----------------
extern "C" void kernel_launch(void* const* d_in, const int* in_sizes, int n_in,
                              void* d_out, int out_size, void* d_ws, size_t ws_size,
                              hipStream_t stream) {
  (void)in_sizes; (void)n_in; (void)out_size; (void)ws_size;
  auto IN = [&](int i) { return (const float*)d_in[i]; };
  char* ws = (char*)d_ws;

  // ws layout
  const size_t OFF_W = 65536;  // PRM: 51*192*4 = 39168 bytes at 0
  static const size_t WSZ[9] = {36864, 73728, 40960, 921600, 73728, 73728, 663552, 73728, 24576};
  f16* WH[9]; f16* WL[9];
  {
    size_t o = OFF_W;
    for (int i = 0; i < 9; ++i) { WH[i] = (f16*)(ws + o); WL[i] = (f16*)(ws + o + WSZ[i]); o += 2 * WSZ[i]; }
  }
  const size_t OFF_ACT = OFF_W + 3964928;
  const size_t SLOT_A = OFF_ACT;
  const size_t SLOT_B = SLOT_A + 83890176;

  f16*   S1P = (f16*)(ws + SLOT_A);
  f16*   S2  = (f16*)(ws + SLOT_B);
  f16*   S3  = (f16*)(ws + SLOT_A);
  float* Y3  = (float*)(ws + SLOT_B);
  f16*   S4P = (f16*)(ws + SLOT_A);
  f16*   S5  = (f16*)(ws + SLOT_B);
  f16*   S6  = (f16*)(ws + SLOT_A);
  float* Y6  = (float*)(ws + SLOT_B);
  f16*   S7P = (f16*)(ws + SLOT_A);
  f16*   S8  = (f16*)(ws + SLOT_B);
  f16*   S9  = (f16*)(ws + SLOT_A);

  float* PRM = (float*)ws;

  PrepAll PA;
  for (int i = 0; i < 9; ++i) {
    PA.pp.g[i]  = IN(1 + i * 6 + 0);
    PA.pp.be[i] = IN(1 + i * 6 + 1);
    PA.pp.m[i]  = IN(1 + i * 6 + 2);
    PA.pp.v[i]  = IN(1 + i * 6 + 3);
    PA.pp.b[i]  = IN(1 + i * 6 + 5);
    PA.w[i] = IN(1 + i * 6 + 4);
    PA.wh[i] = WH[i];
    PA.wl[i] = WL[i];
  }
  PA.pp.ma = IN(55); PA.pp.va = IN(56); PA.pp.mb = IN(57); PA.pp.vb = IN(58);
  PA.x = IN(0);
  PA.s1p = S1P;
  PA.prm = PRM;

  prep_all<<<7761, 256, 0, stream>>>(PA);

  // convs: <MODE,EPI,LOG_HW,LOG_W,CIN,COP,COUT,KH,KW,HP,WP,NCH,CCH>
  convk<2, 1, 10, 5, 3, 192, 192, 5, 5, 36, 36, 3, 1><<<1024 * 3, 256, 0, stream>>>(
      S1P, WH[0], WL[0], PRM + 0 * 960, S2);
  convk<0, 0, 10, 5, 192, 192, 160, 1, 1, 0, 0, 6, 1><<<1024 * 3, 256, 0, stream>>>(
      S2, WH[1], WL[1], PRM + 1 * 960, S3);
  convk<0, 2, 10, 5, 160, 128, 96, 1, 1, 0, 0, 5, 1><<<1024 * 2, 256, 0, stream>>>(
      S3, WH[2], WL[2], PRM + 2 * 960, Y3);
  poolk<32, 96, 16, 20, 2, false><<<9600, 256, 0, stream>>>(Y3, S4P, PRM + 45 * 192, PRM + 46 * 192);
  convk<1, 0, 8, 4, 96, 192, 192, 5, 5, 20, 20, 75, 3><<<256 * 3, 256, 0, stream>>>(
      S4P, WH[3], WL[3], PRM + 3 * 960, S5);
  convk<0, 0, 8, 4, 192, 192, 192, 1, 1, 0, 0, 6, 1><<<256 * 3, 256, 0, stream>>>(
      S5, WH[4], WL[4], PRM + 4 * 960, S6);
  convk<0, 2, 8, 4, 192, 192, 192, 1, 1, 0, 0, 6, 1><<<256 * 3, 256, 0, stream>>>(
      S6, WH[5], WL[5], PRM + 5 * 960, Y6);
  poolk<16, 192, 8, 10, 1, true><<<4800, 256, 0, stream>>>(Y6, S7P, PRM + 47 * 192, PRM + 48 * 192);
  convk<1, 0, 6, 3, 192, 192, 192, 3, 3, 10, 10, 54, 6><<<64 * 3, 256, 0, stream>>>(
      S7P, WH[6], WL[6], PRM + 6 * 960, S8);
  convk<0, 0, 6, 3, 192, 192, 192, 1, 1, 0, 0, 6, 1><<<64 * 3, 256, 0, stream>>>(
      S8, WH[7], WL[7], PRM + 7 * 960, S9);
  convk<0, 3, 6, 3, 192, 64, 10, 1, 1, 0, 0, 6, 1><<<64, 256, 0, stream>>>(
      S9, WH[8], WL[8], PRM + 8 * 960, d_out);
}

// Round 6
// 601.705 us; speedup vs baseline: 6.7656x; 1.0478x over previous
//
#include <hip/hip_runtime.h>
#include <stdint.h>

typedef _Float16 f16;
typedef _Float16 f16x4 __attribute__((ext_vector_type(4)));
typedef _Float16 f16x8 __attribute__((ext_vector_type(8)));
typedef float f32x4 __attribute__((ext_vector_type(4)));

__device__ __forceinline__ float fsgn(float t) {
  return (t > 0.f) ? 1.f : ((t < 0.f) ? -1.f : 0.f);
}

// async global->LDS, 16B per lane; LDS dest = wave-uniform base + lane*16
__device__ __forceinline__ void ldsld16(const void* g, void* l) {
  __builtin_amdgcn_global_load_lds(
      (const __attribute__((address_space(1))) unsigned int*)(unsigned long long)(uintptr_t)g,
      (__attribute__((address_space(3))) unsigned int*)(unsigned int)(uintptr_t)l,
      16, 0, 0);
}

// ---------------- fused prep ----------------
struct PP {
  const float* g[9];
  const float* be[9];
  const float* m[9];
  const float* v[9];
  const float* b[9];
  const float* ma;
  const float* va;
  const float* mb;
  const float* vb;
};

struct PrepAll {
  const float* w[9];
  f16* wh[9];
  f16* wl[9];
  const float* x;
  f16* s1p;
  PP pp;
  float* prm;
};

__device__ void prep_params_body(const PP& a, float* prm) {
  const int c = threadIdx.x;
  if (c >= 192) return;
  const int CINv[9]  = {3, 192, 160, 96, 192, 192, 192, 192, 192};
  const int COUTv[9] = {192, 160, 96, 192, 192, 192, 192, 192, 10};
  auto alpha = [&](int i) { return a.g[i][c] / sqrtf(a.v[i][c] + 1e-4f); };
  auto beta  = [&](int i, float A) { return a.be[i][c] - a.m[i][c] * A; };

  for (int i = 0; i < 9; ++i) {
    float* base = prm + i * 5 * 192;
    base[c] = (c < COUTv[i]) ? a.b[i][c] : 0.f;
    float P1 = 0.f, P2 = 0.f, P3 = 0.f, P4 = 0.f;
    int bn = -1;
    if (i == 0) bn = 1;
    else if (i == 1) bn = 2;
    else if (i == 3) bn = 4;
    else if (i == 4) bn = 5;
    else if (i == 6) bn = 7;
    if (bn >= 0 && c < CINv[bn]) { float A = alpha(bn); P1 = A; P2 = beta(bn, A); }
    if (i == 7) {  // conv8 epilogue: sign(BN9(BN_b(u)))
      float ib = 1.f / sqrtf(a.vb[c] + 1e-4f);
      float A9 = alpha(8);
      P1 = ib * A9;
      P2 = a.be[8][c] - A9 * (a.m[8][c] + a.mb[c] * ib);
    }
    if (i == 0) {  // conv1 epilogue: BN_a (no affine) between relus
      P3 = 1.f / sqrtf(a.va[c] + 1e-4f);
      P4 = a.ma[c] * P3;
    }
    base[192 + c] = P1;
    base[384 + c] = P2;
    base[576 + c] = P3;
    base[768 + c] = P4;
  }
  { float A = (c < 96) ? alpha(3) : 0.f;
    prm[45 * 192 + c] = A; prm[46 * 192 + c] = (c < 96) ? beta(3, A) : 0.f; }
  { float A = alpha(6);
    prm[47 * 192 + c] = A; prm[48 * 192 + c] = beta(6, A); }
  { float A = (c < 3) ? alpha(0) : 0.f;
    prm[49 * 192 + c] = A; prm[50 * 192 + c] = (c < 3) ? beta(0, A) : 0.f; }
}

__device__ void prep_w_body(const float* __restrict__ w, f16* __restrict__ wh,
                            f16* __restrict__ wl, int idx,
                            int Co, int Cin, int KH, int KW, int KP, int mode) {
  const int co = idx / KP;
  const int k = idx - co * KP;
  float val = 0.f;
  if (co < Co) {
    if (mode == 0) {
      if (k < Cin) val = w[(size_t)co * Cin + k];
    } else if (mode == 1) {  // k = (kh*KW+kw)*Cin + c
      int tap = k / Cin, cc = k - tap * Cin;
      int kh = tap / KW, kw = tap - kh * KW;
      val = w[(((size_t)co * Cin + cc) * KH + kh) * KW + kw];
    } else {  // L1: k = kh*16 + kw*3 + c
      int kh = k >> 4, r = k & 15;
      if (kh < 5 && r < 15) {
        int kw = r / 3, cc = r - kw * 3;
        val = w[(((size_t)co * 3 + cc) * 5 + kh) * 5 + kw];
      }
    }
  }
  f16 h = (f16)val;
  float hf = (float)h;
  if (fabsf(hf) < 6.1035e-5f) { h = (f16)0.f; hf = 0.f; }  // no subnormal hi into MFMA
  f16 l = (f16)((val - hf) * 4096.f);                      // lo pre-scaled 2^12
  wh[idx] = h;
  wl[idx] = l;
}

// segment starts: blk0=params; w-layers; then s1
__constant__ int WB[10] = {1, 73, 217, 297, 2097, 2241, 2385, 3681, 3825, 3873};

__global__ void prep_all(PrepAll A) {
  const int b = blockIdx.x;
  if (b == 0) { prep_params_body(A.pp, A.prm); return; }
  if (b < 3873) {
    static const int COv[9]  = {192, 192, 128, 192, 192, 192, 192, 192, 64};  // CoP
    static const int Cov[9]  = {192, 160, 96, 192, 192, 192, 192, 192, 10};   // Co
    static const int CIv[9]  = {3, 192, 160, 96, 192, 192, 192, 192, 192};
    static const int KHv[9]  = {5, 1, 1, 5, 1, 1, 3, 1, 1};
    static const int KPv[9]  = {96, 192, 160, 2400, 192, 192, 1728, 192, 192};
    static const int MDv[9]  = {2, 0, 0, 1, 0, 0, 1, 0, 0};
    int i = 0;
    while (b >= WB[i + 1]) ++i;
    const int idx = (b - WB[i]) * 256 + threadIdx.x;
    if (idx < COv[i] * KPv[i])
      prep_w_body(A.w[i], A.wh[i], A.wl[i], idx, Cov[i], CIv[i], KHv[i], KHv[i], KPv[i], MDv[i]);
    return;
  }
  // s1: sign(BN1(x)) into padded NHWC [256][36][36][3]
  const int idx = (b - 3873) * 256 + threadIdx.x;
  if (idx >= 256 * 36 * 36 * 3) return;
  int c = idx % 3;
  int t = idx / 3;
  int wp = t % 36; t /= 36;
  int hp = t % 36;
  int n = t / 36;
  int h = hp - 2, w = wp - 2;
  f16 s = (f16)0.f;
  if (h >= 0 && h < 32 && w >= 0 && w < 32) {
    float al = A.pp.g[0][c] / sqrtf(A.pp.v[0][c] + 1e-4f);
    float be = A.pp.be[0][c] - A.pp.m[0][c] * al;
    float xv = A.x[((size_t)(n * 3 + c) * 32 + h) * 32 + w];
    s = (f16)fsgn(xv * al + be);
  }
  A.s1p[idx] = s;
}

// ---------------- pool (+BN+sign) into padded NHWC ----------------
template <int HIN, int CH, int HOUT, int HPAD, int POFF, bool AVG>
__global__ void poolk(const float* __restrict__ in, f16* __restrict__ out,
                      const float* __restrict__ pa, const float* __restrict__ pb) {
  constexpr int C4 = CH / 4;
  const int idx = blockIdx.x * 256 + threadIdx.x;
  if (idx >= 256 * HPAD * HPAD * C4) return;
  int c4 = idx % C4;
  int t = idx / C4;
  int wp = t % HPAD; t /= HPAD;
  int hp = t % HPAD;
  int n = t / HPAD;
  int h = hp - POFF, w = wp - POFF;
  f16x4 res;
  res[0] = res[1] = res[2] = res[3] = (f16)0.f;
  if (h >= 0 && h < HOUT && w >= 0 && w < HOUT) {
    float acc[4];
#pragma unroll
    for (int i = 0; i < 4; ++i) acc[i] = AVG ? 0.f : -1e30f;
#pragma unroll
    for (int i = 0; i < 3; ++i) {
      int yh = 2 * h - 1 + i;
      if (yh < 0 || yh >= HIN) continue;
#pragma unroll
      for (int j = 0; j < 3; ++j) {
        int yw = 2 * w - 1 + j;
        if (yw < 0 || yw >= HIN) continue;
        f32x4 vv = *(const f32x4*)(in + ((size_t)(n * HIN + yh) * HIN + yw) * CH + c4 * 4);
#pragma unroll
        for (int k = 0; k < 4; ++k) acc[k] = AVG ? (acc[k] + vv[k]) : fmaxf(acc[k], vv[k]);
      }
    }
    f32x4 A = *(const f32x4*)(pa + c4 * 4);
    f32x4 B = *(const f32x4*)(pb + c4 * 4);
#pragma unroll
    for (int k = 0; k < 4; ++k) {
      float xv = AVG ? (acc[k] / 9.f) : acc[k];
      res[k] = (f16)fsgn(xv * A[k] + B[k]);
    }
  }
  *(f16x4*)(out + (size_t)idx * 4) = res;
}

// ---------------- implicit-GEMM MFMA conv ----------------
// D[co][m] = W[co][k] * P[k][m]; block = 256 m x 64 co, 4 waves (wave: 64m x 64co, 4x4 frags)
// 3-buffer LDS pipeline, counted vmcnt(6), one raw barrier/iter, stage-before-compute,
// XCD-chunked block swizzle (grid always %8==0), setprio around MFMA cluster.
// MODE: 0=1x1, 1=taps-outer (padded input), 2=L1 packed (kh*16+kw*3+c)
// EPI:  0=bias,relu,affine,sign(f16)  1=+BN_a relu between  2=bias,relu->f32  3=bias,relu,mean->out
template <int MODE, int EPI, int LOG_HW, int LOG_W, int CIN, int COP, int COUT,
          int KH, int KW, int HP, int WP, int NCH, int CCH>
__global__ __launch_bounds__(256, 2) void convk(
    const f16* __restrict__ sin, const f16* __restrict__ wh, const f16* __restrict__ wl,
    const float* __restrict__ prm, void* __restrict__ outp) {
  static_assert(NCH >= 3, "pipeline needs >=3 chunks");
  constexpr int NCOB = COP / 64;
  constexpr int HWm = (1 << LOG_HW) - 1;
  constexpr int Wm = (1 << LOG_W) - 1;

  const int tid = threadIdx.x;
  const int wid = tid >> 6;
  const int lane = tid & 63;
  // XCD-chunked bijective swizzle: XCD x (= blockIdx.x%8) owns contiguous logical ids.
  // All conv grids are multiples of 8. Groups same-image cob-triples on one XCD -> L2 reuse.
  const int bid = (blockIdx.x & 7) * ((int)gridDim.x >> 3) + (blockIdx.x >> 3);
  const int mb = bid / NCOB;
  const int cob = bid - mb * NCOB;

  __shared__ __align__(16) char smem[73728];  // 3 x (Ps 16K + Wh 4K + Wl 4K)

  const int pr = lane >> 2;   // row within 16-row staging group
  const int pg = lane & 3;    // physical granule

  // per-lane staging base addresses (granule XOR-swizzle folded into global source)
  const f16* psrc[4];
#pragma unroll
  for (int q = 0; q < 4; ++q) {
    const int j = wid * 4 + q;
    const int r = j * 16 + pr;              // Ps row (m within tile)
    const int g = pg ^ ((r >> 1) & 3);      // logical granule stored at phys pg
    const int m = mb * 256 + r;
    if constexpr (MODE == 0) {
      psrc[q] = sin + (size_t)m * CIN + g * 8;
    } else if constexpr (MODE == 1) {
      const int n = m >> LOG_HW;
      const int hw = m & HWm;
      const int h = hw >> LOG_W;
      const int w = hw & Wm;
      psrc[q] = sin + ((size_t)(n * HP + h) * WP + w) * CIN + g * 8;
    } else {
      const int n = m >> 10;
      const int hw = m & 1023;
      const int h = hw >> 5;
      const int w = hw & 31;
      const int khg = g >> 1;                     // kh = 2*kc + (g>>1)
      const int sel = g & 1;                      // k%16 = 0 or 8
      psrc[q] = sin + ((size_t)(n * 36 + h + khg) * 36 + (w + (sel ? 2 : 0))) * 3 + (sel ? 2 : 0);
    }
  }
  const int wr = wid * 16 + pr;             // Ws row (co within 64-tile)
  const int wgg = pg ^ ((wr >> 1) & 3);
  const f16* wsrc_h = wh + (size_t)(cob * 64 + wr) * (NCH * 32) + wgg * 8;
  const f16* wsrc_l = wl + (size_t)(cob * 64 + wr) * (NCH * 32) + wgg * 8;

  auto stage = [&](int kc, int cur) {
    char* lb = smem + cur * 24576;
    int coff;
    if constexpr (MODE == 0) coff = kc * 32;
    else if constexpr (MODE == 2) coff = kc * 216;  // 2 kh-rows per chunk
    else {
      const int tap = kc / CCH;
      const int cc = kc - tap * CCH;
      const int kh = tap / KW;
      const int kw = tap - kh * KW;
      coff = (kh * WP + kw) * CIN + cc * 32;
    }
#pragma unroll
    for (int q = 0; q < 4; ++q) ldsld16(psrc[q] + coff, lb + (wid * 4 + q) * 1024);
    ldsld16(wsrc_h + kc * 32, lb + 16384 + wid * 1024);
    ldsld16(wsrc_l + kc * 32, lb + 20480 + wid * 1024);
  };

  const int ln15 = lane & 15;
  const int xg = (lane >> 4) ^ ((ln15 >> 1) & 3);  // swizzled read granule
  const int rdB = wid * 4096 + ln15 * 64 + xg * 16;
  const int rdA = 16384 + ln15 * 64 + xg * 16;

  f32x4 aH[4][4], aL[4][4];
#pragma unroll
  for (int a = 0; a < 4; ++a)
#pragma unroll
    for (int b = 0; b < 4; ++b) {
      aH[a][b] = (f32x4){0.f, 0.f, 0.f, 0.f};
      aL[a][b] = (f32x4){0.f, 0.f, 0.f, 0.f};
    }

  auto compute = [&](int cur) {
    const char* cb = smem + cur * 24576;
    f16x8 Bf[4];
#pragma unroll
    for (int a = 0; a < 4; ++a) Bf[a] = *(const f16x8*)(cb + a * 1024 + rdB);
    __builtin_amdgcn_s_setprio(1);
#pragma unroll
    for (int b = 0; b < 4; ++b) {
      const f16x8 Ah = *(const f16x8*)(cb + rdA + b * 1024);
      const f16x8 Al = *(const f16x8*)(cb + rdA + 4096 + b * 1024);
#pragma unroll
      for (int a = 0; a < 4; ++a) {
        aH[a][b] = __builtin_amdgcn_mfma_f32_16x16x32_f16(Ah, Bf[a], aH[a][b], 0, 0, 0);
        aL[a][b] = __builtin_amdgcn_mfma_f32_16x16x32_f16(Al, Bf[a], aL[a][b], 0, 0, 0);
      }
    }
    __builtin_amdgcn_s_setprio(0);
  };

  // prologue: fill buffers 0,1 (12 vmem ops/lane in flight)
  stage(0, 0);
  stage(1, 1);

  // iter s: vmcnt(6) -> stage(s) landed (stage(s+1) in flight); barrier;
  //         issue stage(s+2) (overwrites buf (s-1)%3, consumed before this barrier);
  //         compute(s). One barrier/iter; queue never drained mid-loop.
  for (int s = 0; s < NCH; ++s) {
    if (s == NCH - 1) asm volatile("s_waitcnt vmcnt(0)" ::: "memory");
    else              asm volatile("s_waitcnt vmcnt(6)" ::: "memory");
    __builtin_amdgcn_s_barrier();
    if (s + 2 < NCH) stage(s + 2, (s + 2) % 3);
    compute(s % 3);
  }

  constexpr float LSC = 1.f / 4096.f;
  const int hi4 = (lane >> 4) * 4;

  if constexpr (EPI == 3) {  // conv9: bias, relu, mean over 64 pixels -> d_out
    float red[4] = {0.f, 0.f, 0.f, 0.f};
    const f32x4 bi = *(const f32x4*)(prm + hi4);
#pragma unroll
    for (int a = 0; a < 4; ++a)
#pragma unroll
      for (int i = 0; i < 4; ++i)
        red[i] += fmaxf(aH[a][0][i] + aL[a][0][i] * LSC + bi[i], 0.f);
#pragma unroll
    for (int i = 0; i < 4; ++i) {
      red[i] += __shfl_xor(red[i], 1);
      red[i] += __shfl_xor(red[i], 2);
      red[i] += __shfl_xor(red[i], 4);
      red[i] += __shfl_xor(red[i], 8);
    }
    if (ln15 == 0) {
      const int n = mb * 4 + wid;  // wave owns one image (64 pixels)
      float* o = (float*)outp;
#pragma unroll
      for (int i = 0; i < 4; ++i) {
        const int co = hi4 + i;
        if (co < 10) o[n * 10 + co] = red[i] * (1.f / 64.f);
      }
    }
  } else {
#pragma unroll
    for (int a = 0; a < 4; ++a) {
      const int m = mb * 256 + wid * 64 + a * 16 + ln15;
#pragma unroll
      for (int b = 0; b < 4; ++b) {
        const int co = cob * 64 + b * 16 + hi4;
        if (co < COUT) {
          const f32x4 bi = *(const f32x4*)(prm + co);
          f32x4 v;
#pragma unroll
          for (int i = 0; i < 4; ++i)
            v[i] = fmaxf(aH[a][b][i] + aL[a][b][i] * LSC + bi[i], 0.f);
          if constexpr (EPI == 1) {  // BN_a (no affine) + relu
            const f32x4 ia = *(const f32x4*)(prm + 576 + co);
            const f32x4 mi = *(const f32x4*)(prm + 768 + co);
#pragma unroll
            for (int i = 0; i < 4; ++i) v[i] = fmaxf(v[i] * ia[i] - mi[i], 0.f);
          }
          if constexpr (EPI == 2) {
            *(f32x4*)((float*)outp + (size_t)m * COUT + co) = v;
          } else {
            const f32x4 al = *(const f32x4*)(prm + 192 + co);
            const f32x4 be = *(const f32x4*)(prm + 384 + co);
            f16x4 sgn;
#pragma unroll
            for (int i = 0; i < 4; ++i) sgn[i] = (f16)fsgn(v[i] * al[i] + be[i]);
            *(f16x4*)((f16*)outp + (size_t)m * COUT + co) = sgn;
          }
        }
      }
    }
  }
}

// ---------------- host ----------------
extern "C" void kernel_launch(void* const* d_in, const int* in_sizes, int n_in,
                              void* d_out, int out_size, void* d_ws, size_t ws_size,
                              hipStream_t stream) {
  (void)in_sizes; (void)n_in; (void)out_size; (void)ws_size;
  auto IN = [&](int i) { return (const float*)d_in[i]; };
  char* ws = (char*)d_ws;

  // ws layout
  const size_t OFF_W = 65536;  // PRM: 51*192*4 = 39168 bytes at 0
  static const size_t WSZ[9] = {36864, 73728, 40960, 921600, 73728, 73728, 663552, 73728, 24576};
  f16* WH[9]; f16* WL[9];
  {
    size_t o = OFF_W;
    for (int i = 0; i < 9; ++i) { WH[i] = (f16*)(ws + o); WL[i] = (f16*)(ws + o + WSZ[i]); o += 2 * WSZ[i]; }
  }
  const size_t OFF_ACT = OFF_W + 3964928;
  const size_t SLOT_A = OFF_ACT;
  const size_t SLOT_B = SLOT_A + 83890176;

  f16*   S1P = (f16*)(ws + SLOT_A);
  f16*   S2  = (f16*)(ws + SLOT_B);
  f16*   S3  = (f16*)(ws + SLOT_A);
  float* Y3  = (float*)(ws + SLOT_B);
  f16*   S4P = (f16*)(ws + SLOT_A);
  f16*   S5  = (f16*)(ws + SLOT_B);
  f16*   S6  = (f16*)(ws + SLOT_A);
  float* Y6  = (float*)(ws + SLOT_B);
  f16*   S7P = (f16*)(ws + SLOT_A);
  f16*   S8  = (f16*)(ws + SLOT_B);
  f16*   S9  = (f16*)(ws + SLOT_A);

  float* PRM = (float*)ws;

  PrepAll PA;
  for (int i = 0; i < 9; ++i) {
    PA.pp.g[i]  = IN(1 + i * 6 + 0);
    PA.pp.be[i] = IN(1 + i * 6 + 1);
    PA.pp.m[i]  = IN(1 + i * 6 + 2);
    PA.pp.v[i]  = IN(1 + i * 6 + 3);
    PA.pp.b[i]  = IN(1 + i * 6 + 5);
    PA.w[i] = IN(1 + i * 6 + 4);
    PA.wh[i] = WH[i];
    PA.wl[i] = WL[i];
  }
  PA.pp.ma = IN(55); PA.pp.va = IN(56); PA.pp.mb = IN(57); PA.pp.vb = IN(58);
  PA.x = IN(0);
  PA.s1p = S1P;
  PA.prm = PRM;

  prep_all<<<7761, 256, 0, stream>>>(PA);

  // convs: <MODE,EPI,LOG_HW,LOG_W,CIN,COP,COUT,KH,KW,HP,WP,NCH,CCH>
  convk<2, 1, 10, 5, 3, 192, 192, 5, 5, 36, 36, 3, 1><<<1024 * 3, 256, 0, stream>>>(
      S1P, WH[0], WL[0], PRM + 0 * 960, S2);
  convk<0, 0, 10, 5, 192, 192, 160, 1, 1, 0, 0, 6, 1><<<1024 * 3, 256, 0, stream>>>(
      S2, WH[1], WL[1], PRM + 1 * 960, S3);
  convk<0, 2, 10, 5, 160, 128, 96, 1, 1, 0, 0, 5, 1><<<1024 * 2, 256, 0, stream>>>(
      S3, WH[2], WL[2], PRM + 2 * 960, Y3);
  poolk<32, 96, 16, 20, 2, false><<<9600, 256, 0, stream>>>(Y3, S4P, PRM + 45 * 192, PRM + 46 * 192);
  convk<1, 0, 8, 4, 96, 192, 192, 5, 5, 20, 20, 75, 3><<<256 * 3, 256, 0, stream>>>(
      S4P, WH[3], WL[3], PRM + 3 * 960, S5);
  convk<0, 0, 8, 4, 192, 192, 192, 1, 1, 0, 0, 6, 1><<<256 * 3, 256, 0, stream>>>(
      S5, WH[4], WL[4], PRM + 4 * 960, S6);
  convk<0, 2, 8, 4, 192, 192, 192, 1, 1, 0, 0, 6, 1><<<256 * 3, 256, 0, stream>>>(
      S6, WH[5], WL[5], PRM + 5 * 960, Y6);
  poolk<16, 192, 8, 10, 1, true><<<4800, 256, 0, stream>>>(Y6, S7P, PRM + 47 * 192, PRM + 48 * 192);
  convk<1, 0, 6, 3, 192, 192, 192, 3, 3, 10, 10, 54, 6><<<64 * 3, 256, 0, stream>>>(
      S7P, WH[6], WL[6], PRM + 6 * 960, S8);
  convk<0, 0, 6, 3, 192, 192, 192, 1, 1, 0, 0, 6, 1><<<64 * 3, 256, 0, stream>>>(
      S8, WH[7], WL[7], PRM + 7 * 960, S9);
  convk<0, 3, 6, 3, 192, 64, 10, 1, 1, 0, 0, 6, 1><<<64, 256, 0, stream>>>(
      S9, WH[8], WL[8], PRM + 8 * 960, d_out);
}